// Round 6
// baseline (920.306 us; speedup 1.0000x reference)
//
#include <hip/hip_runtime.h>
#include <hip/hip_bf16.h>
#include <cstdint>
#include <cstddef>

#define DNODE 64
#define HDIM 256
#define NLAYERS 3
#define NCHUNK 4

typedef __attribute__((ext_vector_type(8))) short bf16x8;
typedef __attribute__((ext_vector_type(4))) float f32x4;

__device__ __forceinline__ ushort f2bf(float f) {
    __hip_bfloat16 b = __float2bfloat16(f);
    return *(ushort*)&b;
}
__device__ __forceinline__ float bf2f(ushort u) {
    return __uint_as_float((uint32_t)u << 16);
}
__device__ __forceinline__ unsigned char f2fp8(float f) {
    int p = __builtin_amdgcn_cvt_pk_fp8_f32(f, f, 0, false);
    return (unsigned char)(p & 0xFF);
}

// ---------------------------------------------------------------------------
// k_pre: deg histogram + x->bf16 convert + weight transposes, one launch
// ---------------------------------------------------------------------------
__global__ __launch_bounds__(256) void k_pre(const int* __restrict__ edst, int* __restrict__ deg, int E, int degB,
                                             const float* __restrict__ x, ushort* __restrict__ xb, int n4, int xcB,
                                             const float* __restrict__ w_node, ushort* __restrict__ wnt,
                                             const float* __restrict__ w_gnn, ushort* __restrict__ wgt) {
    int b = blockIdx.x, tid = threadIdx.x;
    if (b < degB) {
        int e = b * 256 + tid;
        if (e < E) atomicAdd(&deg[edst[e]], 1);
    } else if (b < degB + xcB) {
        int i = (b - degB) * 256 + tid;
        if (i < n4) {
            float4 v = *(const float4*)&x[(size_t)i * 4];
            ushort4 o;
            o.x = f2bf(v.x); o.y = f2bf(v.y); o.z = f2bf(v.z); o.w = f2bf(v.w);
            *(ushort4*)&xb[(size_t)i * 4] = o;
        }
    } else {
        int wb = b - degB - xcB;
        int n = tid;
        if (wb < DNODE / 16) {
            int k0 = wb * 16;
#pragma unroll
            for (int i = 0; i < 16; i++)
                wnt[(size_t)n * DNODE + k0 + i] = f2bf(w_node[(size_t)(k0 + i) * HDIM + n]);
        } else {
            wb -= DNODE / 16;
            int l = wb >> 4, k0 = (wb & 15) * 16;
            const float* s = w_gnn + (size_t)l * HDIM * HDIM;
            ushort* d = wgt + (size_t)l * HDIM * HDIM;
#pragma unroll
            for (int i = 0; i < 16; i++)
                d[(size_t)n * HDIM + k0 + i] = f2bf(s[(size_t)(k0 + i) * HDIM + n]);
        }
    }
}

// ---------------------------------------------------------------------------
// Scan chain (unchanged, proven)
// ---------------------------------------------------------------------------
__global__ __launch_bounds__(256) void k_scan_partial(const int* __restrict__ deg, int* __restrict__ bsum, int n) {
    __shared__ int sd[256];
    int tid = threadIdx.x;
    int base = blockIdx.x * 2048 + tid * 8;
    int s = 0;
#pragma unroll
    for (int j = 0; j < 8; j++) {
        int idx = base + j;
        if (idx < n) s += deg[idx];
    }
    sd[tid] = s;
    __syncthreads();
    for (int off = 128; off > 0; off >>= 1) {
        if (tid < off) sd[tid] += sd[tid + off];
        __syncthreads();
    }
    if (tid == 0) bsum[blockIdx.x] = sd[0];
}

__global__ void k_scan_bsum(int* bsum, int nb) {
    if (threadIdx.x == 0 && blockIdx.x == 0) {
        int run = 0;
        for (int i = 0; i < nb; i++) { int v = bsum[i]; bsum[i] = run; run += v; }
    }
}

__global__ __launch_bounds__(256) void k_scan_final(const int* __restrict__ deg, const int* __restrict__ bsum,
                                                    int* __restrict__ row_ptr, int* __restrict__ cursor,
                                                    float* __restrict__ inv_den, int n, int Etot) {
    __shared__ int tsum[256];
    int tid = threadIdx.x;
    int base = blockIdx.x * 2048 + tid * 8;
    int loc[8], dv[8];
    int s = 0;
#pragma unroll
    for (int j = 0; j < 8; j++) {
        int idx = base + j;
        int v = (idx < n) ? deg[idx] : 0;
        dv[j] = v;
        loc[j] = s;
        s += v;
    }
    tsum[tid] = s;
    __syncthreads();
    for (int off = 1; off < 256; off <<= 1) {
        int t = (tid >= off) ? tsum[tid - off] : 0;
        __syncthreads();
        tsum[tid] += t;
        __syncthreads();
    }
    int off0 = bsum[blockIdx.x] + (tid ? tsum[tid - 1] : 0);
#pragma unroll
    for (int j = 0; j < 8; j++) {
        int idx = base + j;
        if (idx < n) {
            int rp = off0 + loc[j];
            row_ptr[idx] = rp;
            cursor[idx] = rp;
            int d = dv[j];
            inv_den[idx] = 1.0f / (float)(d > 0 ? d : 1);
        }
    }
    if (blockIdx.x == 0 && tid == 0) row_ptr[n] = Etot;
}

// ---------------------------------------------------------------------------
// k_fill_proj: CSR fill (NT scattered stores) co-launched with node-proj GEMM
// ---------------------------------------------------------------------------
__global__ __launch_bounds__(256) void k_fill_proj(const int* __restrict__ esrc, const int* __restrict__ edst,
                                                   int* __restrict__ cursor, int* __restrict__ colx, int E, int fillB,
                                                   const ushort* __restrict__ xb, const ushort* __restrict__ wnt,
                                                   const float* __restrict__ bias,
                                                   ushort* __restrict__ hb, unsigned char* __restrict__ h8, int N) {
    int tid = threadIdx.x;
    if ((int)blockIdx.x < fillB) {
        int e = blockIdx.x * 256 + tid;
        if (e < E) {
            int p = atomicAdd(&cursor[edst[e]], 1);
            __builtin_nontemporal_store(esrc[e], &colx[p]);
        }
        return;
    }
    // ---- node projection: 64x64 tile, K=64 ----
    __shared__ ushort As[64][40];
    __shared__ ushort Bs[64][40];
    int gid = blockIdx.x - fillB;
    int row0 = (gid >> 2) * 64, col0 = (gid & 3) * 64;
    int w = tid >> 6, l = tid & 63;
    int sr = tid >> 2, sc = (tid & 3) * 8;
    int wm = (w >> 1) * 32, wn = (w & 1) * 32;
    int fr = l & 15, fk = (l >> 4) * 8;
    f32x4 acc[2][2] = {};

    for (int k0 = 0; k0 < DNODE; k0 += 32) {
        bf16x8 av = {0, 0, 0, 0, 0, 0, 0, 0};
        int gr = row0 + sr;
        if (gr < N) av = *(const bf16x8*)&xb[(size_t)gr * DNODE + k0 + sc];
        *(bf16x8*)&As[sr][sc] = av;
        *(bf16x8*)&Bs[sr][sc] = *(const bf16x8*)&wnt[(size_t)(col0 + sr) * DNODE + k0 + sc];
        __syncthreads();
        bf16x8 af[2], bf[2];
#pragma unroll
        for (int mi = 0; mi < 2; mi++) af[mi] = *(const bf16x8*)&As[wm + mi * 16 + fr][fk];
#pragma unroll
        for (int ni = 0; ni < 2; ni++) bf[ni] = *(const bf16x8*)&Bs[wn + ni * 16 + fr][fk];
#pragma unroll
        for (int mi = 0; mi < 2; mi++)
#pragma unroll
            for (int ni = 0; ni < 2; ni++)
                acc[mi][ni] = __builtin_amdgcn_mfma_f32_16x16x32_bf16(af[mi], bf[ni], acc[mi][ni], 0, 0, 0);
        __syncthreads();
    }

#pragma unroll
    for (int ni = 0; ni < 2; ni++) {
        int gcol = col0 + wn + ni * 16 + fr;
        float bb = bias[gcol];
#pragma unroll
        for (int mi = 0; mi < 2; mi++) {
#pragma unroll
            for (int j = 0; j < 4; j++) {
                int grow = row0 + wm + mi * 16 + (l >> 4) * 4 + j;
                if (grow >= N) continue;
                size_t idx = (size_t)grow * HDIM + gcol;
                float v = acc[mi][ni][j] + bb;
                hb[idx] = f2bf(v);
                h8[idx] = f2fp8(v);
            }
        }
    }
}

// ---------------------------------------------------------------------------
// k_step: chunked pipeline — blocks [0, aggBlocks) aggregate chunk c
// (fp8 gather, proven round-5 body); remaining blocks GEMM chunk c-1.
// LAST: GEMM skips h writes and reduces column sums into g.
// ---------------------------------------------------------------------------
__device__ __forceinline__ void acc_fp8x16(uint4 v, float* acc) {
    uint32_t d[4] = {v.x, v.y, v.z, v.w};
#pragma unroll
    for (int i = 0; i < 4; i++) {
        auto lo = __builtin_amdgcn_cvt_pk_f32_fp8(d[i], false);
        auto hi = __builtin_amdgcn_cvt_pk_f32_fp8(d[i], true);
        acc[i * 4 + 0] += lo[0];
        acc[i * 4 + 1] += lo[1];
        acc[i * 4 + 2] += hi[0];
        acc[i * 4 + 3] += hi[1];
    }
}

template <bool LAST>
__global__ __launch_bounds__(256) void k_step(const unsigned char* __restrict__ h8_in,
                                              ushort* __restrict__ hb,
                                              const int* __restrict__ row_ptr,
                                              const int* __restrict__ colx,
                                              const float* __restrict__ inv_den,
                                              const ushort* __restrict__ Bt,
                                              const float* __restrict__ bias,
                                              ushort* __restrict__ msgb,
                                              unsigned char* __restrict__ h8_out,
                                              float* __restrict__ g,
                                              int aggBase, int aggEnd, int aggBlocks,
                                              int gemmBase, int gemmEnd) {
    int tid = threadIdx.x;
    if ((int)blockIdx.x < aggBlocks) {
        // ---- aggregation (round-5 body, chunk range) ----
        int node = aggBase + (int)blockIdx.x * 16 + (tid >> 4);
        if (node >= aggEnd) return;
        int f = tid & 15;
        int gbase = tid & 48;
        const unsigned char* hp = h8_in + (size_t)f * 16;
        int s = row_ptr[node], e = row_ptr[node + 1];
        float acc[16] = {};
        for (int base = s; base < e; base += 16) {
            int rem = e - base;
            int cnt = rem > 16 ? 16 : rem;
            int cv = (f < cnt) ? colx[base + f] : 0;
            int t = 0;
            for (; t + 3 < cnt; t += 4) {
                int c0 = __shfl(cv, gbase + t);
                int c1 = __shfl(cv, gbase + t + 1);
                int c2 = __shfl(cv, gbase + t + 2);
                int c3 = __shfl(cv, gbase + t + 3);
                uint4 v0 = *(const uint4*)&hp[(size_t)c0 * HDIM];
                uint4 v1 = *(const uint4*)&hp[(size_t)c1 * HDIM];
                uint4 v2 = *(const uint4*)&hp[(size_t)c2 * HDIM];
                uint4 v3 = *(const uint4*)&hp[(size_t)c3 * HDIM];
                acc_fp8x16(v0, acc);
                acc_fp8x16(v1, acc);
                acc_fp8x16(v2, acc);
                acc_fp8x16(v3, acc);
            }
            for (; t < cnt; t++) {
                int c0 = __shfl(cv, gbase + t);
                uint4 v0 = *(const uint4*)&hp[(size_t)c0 * HDIM];
                acc_fp8x16(v0, acc);
            }
        }
        float inv = inv_den[node];
        ushort o[16];
#pragma unroll
        for (int k = 0; k < 16; k++) o[k] = f2bf(acc[k] * inv);
        ushort* mp = &msgb[(size_t)node * HDIM + f * 16];
        *(uint4*)&mp[0] = *(uint4*)&o[0];
        *(uint4*)&mp[8] = *(uint4*)&o[8];
        return;
    }

    // ---- GEMM: h = relu(h + msg @ Wt^T + bias), rows [gemmBase, gemmEnd) ----
    __shared__ ushort As[64][40];
    __shared__ ushort Bs[64][40];
    __shared__ float cols[256];
    int gid = blockIdx.x - aggBlocks;
    int row0 = gemmBase + (gid >> 2) * 64, col0 = (gid & 3) * 64;
    int w = tid >> 6, l = tid & 63;
    int sr = tid >> 2, sc = (tid & 3) * 8;
    int wm = (w >> 1) * 32, wn = (w & 1) * 32;
    int fr = l & 15, fk = (l >> 4) * 8;
    f32x4 acc[2][2] = {};

    for (int k0 = 0; k0 < HDIM; k0 += 32) {
        bf16x8 av = {0, 0, 0, 0, 0, 0, 0, 0};
        int gr = row0 + sr;
        if (gr < gemmEnd) av = *(const bf16x8*)&msgb[(size_t)gr * HDIM + k0 + sc];
        *(bf16x8*)&As[sr][sc] = av;
        *(bf16x8*)&Bs[sr][sc] = *(const bf16x8*)&Bt[(size_t)(col0 + sr) * HDIM + k0 + sc];
        __syncthreads();
        bf16x8 af[2], bf[2];
#pragma unroll
        for (int mi = 0; mi < 2; mi++) af[mi] = *(const bf16x8*)&As[wm + mi * 16 + fr][fk];
#pragma unroll
        for (int ni = 0; ni < 2; ni++) bf[ni] = *(const bf16x8*)&Bs[wn + ni * 16 + fr][fk];
#pragma unroll
        for (int mi = 0; mi < 2; mi++)
#pragma unroll
            for (int ni = 0; ni < 2; ni++)
                acc[mi][ni] = __builtin_amdgcn_mfma_f32_16x16x32_bf16(af[mi], bf[ni], acc[mi][ni], 0, 0, 0);
        __syncthreads();
    }

    if (LAST) {
        cols[tid] = 0.f;
        __syncthreads();
    }
#pragma unroll
    for (int ni = 0; ni < 2; ni++) {
        int gcol = col0 + wn + ni * 16 + fr;
        float bb = bias[gcol];
        float csum = 0.f;
#pragma unroll
        for (int mi = 0; mi < 2; mi++) {
#pragma unroll
            for (int j = 0; j < 4; j++) {
                int grow = row0 + wm + mi * 16 + (l >> 4) * 4 + j;
                if (grow >= gemmEnd) continue;
                size_t idx = (size_t)grow * HDIM + gcol;
                float v = acc[mi][ni][j] + bb + bf2f(hb[idx]);
                v = fmaxf(v, 0.f);
                if (LAST) {
                    csum += v;
                } else {
                    hb[idx] = f2bf(v);
                    h8_out[idx] = f2fp8(v);
                }
            }
        }
        if (LAST) atomicAdd(&cols[gcol], csum);
    }
    if (LAST) {
        __syncthreads();
        atomicAdd(&g[tid], cols[tid]);
    }
}

// ---------------------------------------------------------------------------
// Tiny MLP head (fp32)
// ---------------------------------------------------------------------------
__global__ __launch_bounds__(256) void k_mlp(const float* __restrict__ g, const float* __restrict__ w1,
                                             const float* __restrict__ b1, const float* __restrict__ w2,
                                             const float* __restrict__ b2, float* __restrict__ out, float invN) {
    __shared__ float gs[256];
    __shared__ float ts[256];
    int f = threadIdx.x;
    gs[f] = g[f] * invN;
    __syncthreads();
    float a = b1[f];
    for (int k = 0; k < 256; k++) a = fmaf(gs[k], w1[k * 256 + f], a);
    ts[f] = fmaxf(a, 0.f);
    __syncthreads();
    float o = b2[f];
    for (int k = 0; k < 256; k++) o = fmaf(ts[k], w2[k * 256 + f], o);
    out[f] = o;
}

// ---------------------------------------------------------------------------
extern "C" void kernel_launch(void* const* d_in, const int* in_sizes, int n_in,
                              void* d_out, int out_size, void* d_ws, size_t ws_size,
                              hipStream_t stream) {
    const float* x      = (const float*)d_in[0];
    const int*   src    = (const int*)d_in[1];
    const int*   dst    = (const int*)d_in[2];
    const float* w_node = (const float*)d_in[3];
    const float* b_node = (const float*)d_in[4];
    const float* w_gnn  = (const float*)d_in[5];
    const float* b_gnn  = (const float*)d_in[6];
    const float* w_p1   = (const float*)d_in[7];
    const float* b_p1   = (const float*)d_in[8];
    const float* w_p2   = (const float*)d_in[9];
    const float* b_p2   = (const float*)d_in[10];
    float* out = (float*)d_out;

    const int N = in_sizes[0] / DNODE;  // 100000
    const int E = in_sizes[1];          // 1600000

    // workspace layout (~175 MB)
    char* w = (char*)d_ws;
    ushort* hb     = (ushort*)w;            w += (size_t)N * HDIM * 2;
    ushort* msgb   = (ushort*)w;            w += (size_t)N * HDIM * 2;
    unsigned char* h8A = (unsigned char*)w; w += (size_t)N * HDIM;
    unsigned char* h8B = (unsigned char*)w; w += (size_t)N * HDIM;
    ushort* xb     = (ushort*)w;            w += (size_t)N * DNODE * 2;
    ushort* wnt    = (ushort*)w;            w += (size_t)HDIM * DNODE * 2;
    ushort* wgt    = (ushort*)w;            w += (size_t)NLAYERS * HDIM * HDIM * 2;
    int*   deg     = (int*)w;               w += (size_t)N * 4;
    int*   row_ptr = (int*)w;               w += (size_t)(N + 1) * 4;
    int*   cursor  = (int*)w;               w += (size_t)N * 4;
    int*   colx    = (int*)w;               w += (size_t)E * 4;
    float* inv_den = (float*)w;             w += (size_t)N * 4;
    float* g       = (float*)w;             w += 256 * 4;
    int*   bsum    = (int*)w;               w += 256 * 4;
    (void)ws_size; (void)n_in; (void)out_size;

    hipMemsetAsync(deg, 0, (size_t)N * 4, stream);
    hipMemsetAsync(g, 0, 256 * 4, stream);

    // deg histogram + converts (one launch)
    int degB = (E + 255) / 256;
    int n4 = N * DNODE / 4;
    int xcB = (n4 + 255) / 256;
    int wcB = DNODE / 16 + NLAYERS * (HDIM / 16);
    k_pre<<<degB + xcB + wcB, 256, 0, stream>>>(dst, deg, E, degB, x, xb, n4, xcB,
                                                w_node, wnt, w_gnn, wgt);

    // scan chain
    int nb = (N + 2047) / 2048;
    k_scan_partial<<<nb, 256, 0, stream>>>(deg, bsum, N);
    k_scan_bsum<<<1, 64, 0, stream>>>(bsum, nb);
    k_scan_final<<<nb, 256, 0, stream>>>(deg, bsum, row_ptr, cursor, inv_den, N, E);

    // CSR fill + node projection (one launch)
    int fillB = (E + 255) / 256;
    int projB = 4 * ((N + 63) / 64);
    k_fill_proj<<<fillB + projB, 256, 0, stream>>>(src, dst, cursor, colx, E, fillB,
                                                   xb, wnt, b_node, hb, h8A, N);

    // chunk boundaries (multiples of 64)
    int chunk = (((N + NCHUNK - 1) / NCHUNK) + 63) & ~63;
    int cb[NCHUNK + 1];
    for (int i = 0; i <= NCHUNK; i++) {
        long v = (long)i * chunk;
        cb[i] = v > N ? N : (int)v;
    }

    // GNN layers: pipelined agg(chunk c) || gemm(chunk c-1)
    for (int l = 0; l < NLAYERS; l++) {
        const ushort* Bt = wgt + (size_t)l * HDIM * HDIM;
        const float* bg = b_gnn + (size_t)l * HDIM;
        const unsigned char* h8in = (l & 1) ? h8B : h8A;
        unsigned char* h8out = (l & 1) ? h8A : h8B;
        bool last = (l == NLAYERS - 1);
        for (int s = 0; s <= NCHUNK; s++) {
            int aBase = 0, aEnd = 0, aBlocks = 0;
            if (s < NCHUNK) {
                aBase = cb[s]; aEnd = cb[s + 1];
                aBlocks = (aEnd - aBase + 15) / 16;
            }
            int gBase = 0, gEnd = 0, gBlocks = 0;
            if (s > 0) {
                gBase = cb[s - 1]; gEnd = cb[s];
                gBlocks = 4 * ((gEnd - gBase + 63) / 64);
            }
            int grid = aBlocks + gBlocks;
            if (grid == 0) continue;
            if (last)
                k_step<true><<<grid, 256, 0, stream>>>(h8in, hb, row_ptr, colx, inv_den, Bt, bg,
                                                       msgb, nullptr, g,
                                                       aBase, aEnd, aBlocks, gBase, gEnd);
            else
                k_step<false><<<grid, 256, 0, stream>>>(h8in, hb, row_ptr, colx, inv_den, Bt, bg,
                                                        msgb, h8out, nullptr,
                                                        aBase, aEnd, aBlocks, gBase, gEnd);
        }
    }

    k_mlp<<<1, 256, 0, stream>>>(g, w_p1, b_p1, w_p2, b_p2, out, 1.0f / (float)N);
}

// Round 7
// 617.492 us; speedup vs baseline: 1.4904x; 1.4904x over previous
//
#include <hip/hip_runtime.h>
#include <hip/hip_bf16.h>
#include <cstdint>
#include <cstddef>

#define DNODE 64
#define HDIM 256
#define NLAYERS 3
#define NPART 8

typedef __attribute__((ext_vector_type(8))) short bf16x8;
typedef __attribute__((ext_vector_type(4))) float f32x4;

__device__ __forceinline__ ushort f2bf(float f) {
    __hip_bfloat16 b = __float2bfloat16(f);
    return *(ushort*)&b;
}
__device__ __forceinline__ float bf2f(ushort u) {
    return __uint_as_float((uint32_t)u << 16);
}
__device__ __forceinline__ unsigned char f2fp8(float f) {
    int p = __builtin_amdgcn_cvt_pk_fp8_f32(f, f, 0, false);
    return (unsigned char)(p & 0xFF);
}

// ---------------------------------------------------------------------------
// k_pre: deg histogram + x->bf16 convert + weight transposes, one launch
// ---------------------------------------------------------------------------
__global__ __launch_bounds__(256) void k_pre(const int* __restrict__ edst, int* __restrict__ deg, int E, int degB,
                                             const float* __restrict__ x, ushort* __restrict__ xb, int n4, int xcB,
                                             const float* __restrict__ w_node, ushort* __restrict__ wnt,
                                             const float* __restrict__ w_gnn, ushort* __restrict__ wgt) {
    int b = blockIdx.x, tid = threadIdx.x;
    if (b < degB) {
        int e = b * 256 + tid;
        if (e < E) atomicAdd(&deg[edst[e]], 1);
    } else if (b < degB + xcB) {
        int i = (b - degB) * 256 + tid;
        if (i < n4) {
            float4 v = *(const float4*)&x[(size_t)i * 4];
            ushort4 o;
            o.x = f2bf(v.x); o.y = f2bf(v.y); o.z = f2bf(v.z); o.w = f2bf(v.w);
            *(ushort4*)&xb[(size_t)i * 4] = o;
        }
    } else {
        int wb = b - degB - xcB;
        int n = tid;
        if (wb < DNODE / 16) {
            int k0 = wb * 16;
#pragma unroll
            for (int i = 0; i < 16; i++)
                wnt[(size_t)n * DNODE + k0 + i] = f2bf(w_node[(size_t)(k0 + i) * HDIM + n]);
        } else {
            wb -= DNODE / 16;
            int l = wb >> 4, k0 = (wb & 15) * 16;
            const float* s = w_gnn + (size_t)l * HDIM * HDIM;
            ushort* d = wgt + (size_t)l * HDIM * HDIM;
#pragma unroll
            for (int i = 0; i < 16; i++)
                d[(size_t)n * HDIM + k0 + i] = f2bf(s[(size_t)(k0 + i) * HDIM + n]);
        }
    }
}

// ---------------------------------------------------------------------------
// Scan chain (unchanged, proven)
// ---------------------------------------------------------------------------
__global__ __launch_bounds__(256) void k_scan_partial(const int* __restrict__ deg, int* __restrict__ bsum, int n) {
    __shared__ int sd[256];
    int tid = threadIdx.x;
    int base = blockIdx.x * 2048 + tid * 8;
    int s = 0;
#pragma unroll
    for (int j = 0; j < 8; j++) {
        int idx = base + j;
        if (idx < n) s += deg[idx];
    }
    sd[tid] = s;
    __syncthreads();
    for (int off = 128; off > 0; off >>= 1) {
        if (tid < off) sd[tid] += sd[tid + off];
        __syncthreads();
    }
    if (tid == 0) bsum[blockIdx.x] = sd[0];
}

__global__ void k_scan_bsum(int* bsum, int nb) {
    if (threadIdx.x == 0 && blockIdx.x == 0) {
        int run = 0;
        for (int i = 0; i < nb; i++) { int v = bsum[i]; bsum[i] = run; run += v; }
    }
}

__global__ __launch_bounds__(256) void k_scan_final(const int* __restrict__ deg, const int* __restrict__ bsum,
                                                    int* __restrict__ row_ptr, int* __restrict__ cursor,
                                                    float* __restrict__ inv_den, int n, int Etot) {
    __shared__ int tsum[256];
    int tid = threadIdx.x;
    int base = blockIdx.x * 2048 + tid * 8;
    int loc[8], dv[8];
    int s = 0;
#pragma unroll
    for (int j = 0; j < 8; j++) {
        int idx = base + j;
        int v = (idx < n) ? deg[idx] : 0;
        dv[j] = v;
        loc[j] = s;
        s += v;
    }
    tsum[tid] = s;
    __syncthreads();
    for (int off = 1; off < 256; off <<= 1) {
        int t = (tid >= off) ? tsum[tid - off] : 0;
        __syncthreads();
        tsum[tid] += t;
        __syncthreads();
    }
    int off0 = bsum[blockIdx.x] + (tid ? tsum[tid - 1] : 0);
#pragma unroll
    for (int j = 0; j < 8; j++) {
        int idx = base + j;
        if (idx < n) {
            int rp = off0 + loc[j];
            row_ptr[idx] = rp;
            cursor[idx] = rp;
            int d = dv[j];
            inv_den[idx] = 1.0f / (float)(d > 0 ? d : 1);
        }
    }
    if (blockIdx.x == 0 && tid == 0) row_ptr[n] = Etot;
}

// ---------------------------------------------------------------------------
// k_fill_part: XCD-partitioned CSR fill. Partition p = blockIdx&7 handles
// dst range [p*npp, (p+1)*npp); blockIdx round-robins across the 8 XCDs so
// each partition's colx region (~0.8MB) stays L2-resident on one XCD and
// each 64B line absorbs all its ~16 scattered 4B writes before writeback.
// ---------------------------------------------------------------------------
__global__ __launch_bounds__(256) void k_fill_part(const int* __restrict__ esrc, const int* __restrict__ edst,
                                                   int* __restrict__ cursor, int* __restrict__ colx,
                                                   int E, int npp, int nslices) {
    int part = blockIdx.x & (NPART - 1);
    int slice = blockIdx.x / NPART;
    int lo = part * npp;
    int hi = lo + npp;
    int stride = nslices * 256;
    for (int e = slice * 256 + (int)threadIdx.x; e < E; e += stride) {
        int d = edst[e];
        if (d >= lo && d < hi) {
            int p = atomicAdd(&cursor[d], 1);
            colx[p] = esrc[e];
        }
    }
}

// ---------------------------------------------------------------------------
// Aggregation (round-5 proven): fp8 gather, one node per 16-lane group,
// 4-deep edge unroll, fp32 acc, bf16 msg out.
// ---------------------------------------------------------------------------
__device__ __forceinline__ void acc_fp8x16(uint4 v, float* acc) {
    uint32_t d[4] = {v.x, v.y, v.z, v.w};
#pragma unroll
    for (int i = 0; i < 4; i++) {
        auto lo = __builtin_amdgcn_cvt_pk_f32_fp8(d[i], false);
        auto hi = __builtin_amdgcn_cvt_pk_f32_fp8(d[i], true);
        acc[i * 4 + 0] += lo[0];
        acc[i * 4 + 1] += lo[1];
        acc[i * 4 + 2] += hi[0];
        acc[i * 4 + 3] += hi[1];
    }
}

__global__ __launch_bounds__(256) void k_aggregate_fp8(const unsigned char* __restrict__ h8,
                                                       const int* __restrict__ row_ptr,
                                                       const int* __restrict__ colx,
                                                       const float* __restrict__ inv_den,
                                                       ushort* __restrict__ msgb, int N) {
    int tid = threadIdx.x;
    int node = blockIdx.x * 16 + (tid >> 4);
    if (node >= N) return;
    int f = tid & 15;
    int gbase = tid & 48;
    const unsigned char* hp = h8 + (size_t)f * 16;

    int s = row_ptr[node], e = row_ptr[node + 1];
    float acc[16] = {};

    for (int base = s; base < e; base += 16) {
        int rem = e - base;
        int cnt = rem > 16 ? 16 : rem;
        int cv = (f < cnt) ? colx[base + f] : 0;
        int t = 0;
        for (; t + 3 < cnt; t += 4) {
            int c0 = __shfl(cv, gbase + t);
            int c1 = __shfl(cv, gbase + t + 1);
            int c2 = __shfl(cv, gbase + t + 2);
            int c3 = __shfl(cv, gbase + t + 3);
            uint4 v0 = *(const uint4*)&hp[(size_t)c0 * HDIM];
            uint4 v1 = *(const uint4*)&hp[(size_t)c1 * HDIM];
            uint4 v2 = *(const uint4*)&hp[(size_t)c2 * HDIM];
            uint4 v3 = *(const uint4*)&hp[(size_t)c3 * HDIM];
            acc_fp8x16(v0, acc);
            acc_fp8x16(v1, acc);
            acc_fp8x16(v2, acc);
            acc_fp8x16(v3, acc);
        }
        for (; t < cnt; t++) {
            int c0 = __shfl(cv, gbase + t);
            uint4 v0 = *(const uint4*)&hp[(size_t)c0 * HDIM];
            acc_fp8x16(v0, acc);
        }
    }

    float inv = inv_den[node];
    ushort o[16];
#pragma unroll
    for (int k = 0; k < 16; k++) o[k] = f2bf(acc[k] * inv);
    ushort* mp = &msgb[(size_t)node * HDIM + f * 16];
    *(uint4*)&mp[0] = *(uint4*)&o[0];
    *(uint4*)&mp[8] = *(uint4*)&o[8];
}

// ---------------------------------------------------------------------------
// bf16 MFMA GEMM (round-5 proven): H = act((ADD?H:0) + A @ Bt^T + bias)
// ---------------------------------------------------------------------------
template <bool ADD, bool RELU, bool W8>
__global__ __launch_bounds__(256) void k_gemm_mfma(const ushort* __restrict__ A,
                                                   const ushort* __restrict__ Bt,
                                                   const float* __restrict__ bias,
                                                   ushort* __restrict__ H,
                                                   unsigned char* __restrict__ H8,
                                                   int M, int K) {
    __shared__ ushort As[64][40];
    __shared__ ushort Bs[64][40];
    int tid = threadIdx.x;
    int w = tid >> 6, l = tid & 63;
    int row0 = blockIdx.y * 64, col0 = blockIdx.x * 64;
    int sr = tid >> 2, sc = (tid & 3) * 8;
    int wm = (w >> 1) * 32, wn = (w & 1) * 32;
    int fr = l & 15, fk = (l >> 4) * 8;
    f32x4 acc[2][2] = {};

    for (int k0 = 0; k0 < K; k0 += 32) {
        bf16x8 av = {0, 0, 0, 0, 0, 0, 0, 0};
        int gr = row0 + sr;
        if (gr < M) av = *(const bf16x8*)&A[(size_t)gr * K + k0 + sc];
        *(bf16x8*)&As[sr][sc] = av;
        *(bf16x8*)&Bs[sr][sc] = *(const bf16x8*)&Bt[(size_t)(col0 + sr) * K + k0 + sc];
        __syncthreads();
        bf16x8 af[2], bf[2];
#pragma unroll
        for (int mi = 0; mi < 2; mi++) af[mi] = *(const bf16x8*)&As[wm + mi * 16 + fr][fk];
#pragma unroll
        for (int ni = 0; ni < 2; ni++) bf[ni] = *(const bf16x8*)&Bs[wn + ni * 16 + fr][fk];
#pragma unroll
        for (int mi = 0; mi < 2; mi++)
#pragma unroll
            for (int ni = 0; ni < 2; ni++)
                acc[mi][ni] = __builtin_amdgcn_mfma_f32_16x16x32_bf16(af[mi], bf[ni], acc[mi][ni], 0, 0, 0);
        __syncthreads();
    }

#pragma unroll
    for (int ni = 0; ni < 2; ni++) {
        int gcol = col0 + wn + ni * 16 + fr;
        float bb = bias[gcol];
#pragma unroll
        for (int mi = 0; mi < 2; mi++) {
#pragma unroll
            for (int j = 0; j < 4; j++) {
                int grow = row0 + wm + mi * 16 + (l >> 4) * 4 + j;
                if (grow >= M) continue;
                size_t idx = (size_t)grow * HDIM + gcol;
                float v = acc[mi][ni][j] + bb;
                if (ADD) v += bf2f(H[idx]);
                if (RELU) v = fmaxf(v, 0.f);
                H[idx] = f2bf(v);
                if (W8) H8[idx] = f2fp8(v);
            }
        }
    }
}

// ---------------------------------------------------------------------------
// Last-layer GEMM: relu(hb + msg @ Wt^T + bias), no h writes; column sums
// reduced in LDS then atomically added to g (body validated in round 6).
// ---------------------------------------------------------------------------
__global__ __launch_bounds__(256) void k_gemm_last(const ushort* __restrict__ A,
                                                   const ushort* __restrict__ Bt,
                                                   const float* __restrict__ bias,
                                                   const ushort* __restrict__ H,
                                                   float* __restrict__ g,
                                                   int M) {
    __shared__ ushort As[64][40];
    __shared__ ushort Bs[64][40];
    __shared__ float cols[256];
    int tid = threadIdx.x;
    int w = tid >> 6, l = tid & 63;
    int row0 = blockIdx.y * 64, col0 = blockIdx.x * 64;
    int sr = tid >> 2, sc = (tid & 3) * 8;
    int wm = (w >> 1) * 32, wn = (w & 1) * 32;
    int fr = l & 15, fk = (l >> 4) * 8;
    f32x4 acc[2][2] = {};

    for (int k0 = 0; k0 < HDIM; k0 += 32) {
        bf16x8 av = {0, 0, 0, 0, 0, 0, 0, 0};
        int gr = row0 + sr;
        if (gr < M) av = *(const bf16x8*)&A[(size_t)gr * HDIM + k0 + sc];
        *(bf16x8*)&As[sr][sc] = av;
        *(bf16x8*)&Bs[sr][sc] = *(const bf16x8*)&Bt[(size_t)(col0 + sr) * HDIM + k0 + sc];
        __syncthreads();
        bf16x8 af[2], bf[2];
#pragma unroll
        for (int mi = 0; mi < 2; mi++) af[mi] = *(const bf16x8*)&As[wm + mi * 16 + fr][fk];
#pragma unroll
        for (int ni = 0; ni < 2; ni++) bf[ni] = *(const bf16x8*)&Bs[wn + ni * 16 + fr][fk];
#pragma unroll
        for (int mi = 0; mi < 2; mi++)
#pragma unroll
            for (int ni = 0; ni < 2; ni++)
                acc[mi][ni] = __builtin_amdgcn_mfma_f32_16x16x32_bf16(af[mi], bf[ni], acc[mi][ni], 0, 0, 0);
        __syncthreads();
    }

    cols[tid] = 0.f;
    __syncthreads();
#pragma unroll
    for (int ni = 0; ni < 2; ni++) {
        int gcol = col0 + wn + ni * 16 + fr;
        float bb = bias[gcol];
        float csum = 0.f;
#pragma unroll
        for (int mi = 0; mi < 2; mi++) {
#pragma unroll
            for (int j = 0; j < 4; j++) {
                int grow = row0 + wm + mi * 16 + (l >> 4) * 4 + j;
                if (grow >= M) continue;
                size_t idx = (size_t)grow * HDIM + gcol;
                float v = acc[mi][ni][j] + bb + bf2f(H[idx]);
                csum += fmaxf(v, 0.f);
            }
        }
        atomicAdd(&cols[gcol], csum);
    }
    __syncthreads();
    if (tid < 64) atomicAdd(&g[col0 + tid], cols[col0 + tid]);
}

// ---------------------------------------------------------------------------
// Tiny MLP head (fp32)
// ---------------------------------------------------------------------------
__global__ __launch_bounds__(256) void k_mlp(const float* __restrict__ g, const float* __restrict__ w1,
                                             const float* __restrict__ b1, const float* __restrict__ w2,
                                             const float* __restrict__ b2, float* __restrict__ out, float invN) {
    __shared__ float gs[256];
    __shared__ float ts[256];
    int f = threadIdx.x;
    gs[f] = g[f] * invN;
    __syncthreads();
    float a = b1[f];
    for (int k = 0; k < 256; k++) a = fmaf(gs[k], w1[k * 256 + f], a);
    ts[f] = fmaxf(a, 0.f);
    __syncthreads();
    float o = b2[f];
    for (int k = 0; k < 256; k++) o = fmaf(ts[k], w2[k * 256 + f], o);
    out[f] = o;
}

// ---------------------------------------------------------------------------
extern "C" void kernel_launch(void* const* d_in, const int* in_sizes, int n_in,
                              void* d_out, int out_size, void* d_ws, size_t ws_size,
                              hipStream_t stream) {
    const float* x      = (const float*)d_in[0];
    const int*   src    = (const int*)d_in[1];
    const int*   dst    = (const int*)d_in[2];
    const float* w_node = (const float*)d_in[3];
    const float* b_node = (const float*)d_in[4];
    const float* w_gnn  = (const float*)d_in[5];
    const float* b_gnn  = (const float*)d_in[6];
    const float* w_p1   = (const float*)d_in[7];
    const float* b_p1   = (const float*)d_in[8];
    const float* w_p2   = (const float*)d_in[9];
    const float* b_p2   = (const float*)d_in[10];
    float* out = (float*)d_out;

    const int N = in_sizes[0] / DNODE;  // 100000
    const int E = in_sizes[1];          // 1600000

    // workspace layout (~155 MB)
    char* w = (char*)d_ws;
    ushort* hb     = (ushort*)w;            w += (size_t)N * HDIM * 2;
    ushort* msgb   = (ushort*)w;            w += (size_t)N * HDIM * 2;
    unsigned char* h8 = (unsigned char*)w;  w += (size_t)N * HDIM;
    ushort* xb     = (ushort*)w;            w += (size_t)N * DNODE * 2;
    ushort* wnt    = (ushort*)w;            w += (size_t)HDIM * DNODE * 2;
    ushort* wgt    = (ushort*)w;            w += (size_t)NLAYERS * HDIM * HDIM * 2;
    int*   deg     = (int*)w;               w += (size_t)N * 4;
    int*   row_ptr = (int*)w;               w += (size_t)(N + 1) * 4;
    int*   cursor  = (int*)w;               w += (size_t)N * 4;
    int*   colx    = (int*)w;               w += (size_t)E * 4;
    float* inv_den = (float*)w;             w += (size_t)N * 4;
    float* g       = (float*)w;             w += 256 * 4;
    int*   bsum    = (int*)w;               w += 256 * 4;
    (void)ws_size; (void)n_in; (void)out_size;

    hipMemsetAsync(deg, 0, (size_t)N * 4, stream);
    hipMemsetAsync(g, 0, 256 * 4, stream);

    // deg histogram + converts (one launch)
    int degB = (E + 255) / 256;
    int n4 = N * DNODE / 4;
    int xcB = (n4 + 255) / 256;
    int wcB = DNODE / 16 + NLAYERS * (HDIM / 16);
    k_pre<<<degB + xcB + wcB, 256, 0, stream>>>(dst, deg, E, degB, x, xb, n4, xcB,
                                                w_node, wnt, w_gnn, wgt);

    // scan chain
    int nb = (N + 2047) / 2048;
    k_scan_partial<<<nb, 256, 0, stream>>>(deg, bsum, N);
    k_scan_bsum<<<1, 64, 0, stream>>>(bsum, nb);
    k_scan_final<<<nb, 256, 0, stream>>>(deg, bsum, row_ptr, cursor, inv_den, N, E);

    // CSR fill — XCD-partitioned for colx L2 residency
    int npp = (N + NPART - 1) / NPART;
    int nslices = 256;
    k_fill_part<<<NPART * nslices, 256, 0, stream>>>(src, dst, cursor, colx, E, npp, nslices);

    // node projection -> hb + h8
    dim3 gg(HDIM / 64, (N + 63) / 64);
    k_gemm_mfma<false, false, true><<<gg, 256, 0, stream>>>(xb, wnt, b_node, hb, h8, N, DNODE);

    // GNN layers
    int nagg = (N + 15) / 16;
    for (int l = 0; l < NLAYERS; l++) {
        k_aggregate_fp8<<<nagg, 256, 0, stream>>>(h8, row_ptr, colx, inv_den, msgb, N);
        const ushort* Bt = wgt + (size_t)l * HDIM * HDIM;
        const float* bg = b_gnn + (size_t)l * HDIM;
        if (l < NLAYERS - 1)
            k_gemm_mfma<true, true, true><<<gg, 256, 0, stream>>>(msgb, Bt, bg, hb, h8, N, HDIM);
        else
            k_gemm_last<<<gg, 256, 0, stream>>>(msgb, Bt, bg, hb, g, N);
    }

    k_mlp<<<1, 256, 0, stream>>>(g, w_p1, b_p1, w_p2, b_p2, out, 1.0f / (float)N);
}